// Round 4
// baseline (1130.222 us; speedup 1.0000x reference)
//
#include <hip/hip_runtime.h>
#include <hip/hip_bf16.h>
#include <stdint.h>
#include <stddef.h>

#define BB 2
#define NN 384
#define DD 768
#define HH 256
#define SS 64
#define NHH 8
#define DHH 96

typedef __attribute__((ext_vector_type(8))) short bf16x8;
typedef __attribute__((ext_vector_type(4))) float f32x4;

__device__ __forceinline__ float bits_f(unsigned short u){
  unsigned x = ((unsigned)u) << 16; float f; __builtin_memcpy(&f, &x, 4); return f;
}
__device__ __forceinline__ unsigned short f_bits(float a){
  unsigned x; __builtin_memcpy(&x, &a, 4);
  unsigned r = x + 0x7fffu + ((x >> 16) & 1u);
  return (unsigned short)(r >> 16);
}
__device__ __forceinline__ float lo_f(unsigned u){ unsigned x = u << 16; float f; __builtin_memcpy(&f,&x,4); return f; }
__device__ __forceinline__ float hi_f(unsigned u){ unsigned x = u & 0xffff0000u; float f; __builtin_memcpy(&f,&x,4); return f; }

// ---------------- prep: transpose ge_w2 [256,768] fp32 -> w2T [768,256] bf16 ----------------
__global__ void k_prep(const float* __restrict__ w2, short* __restrict__ w2T){
  int idx = blockIdx.x * 256 + threadIdx.x;           // 0 .. 196607
  int d = idx >> 8, k = idx & 255;
  w2T[idx] = (short)f_bits(w2[k * DD + d]);
}

// ---------------- fused geometric encoder + mean over j ----------------
// one WG per (b,i); 512 threads = 8 waves; j tiled by 64
__global__ __launch_bounds__(512) void k_geo(
    const float* __restrict__ coord,
    const float* __restrict__ w1g,
    const float* __restrict__ b1g, const float* __restrict__ g1g,
    const float* __restrict__ be1g,
    const float* __restrict__ b2g, const float* __restrict__ g2g,
    const float* __restrict__ be2g,
    const short* __restrict__ w2T, unsigned short* __restrict__ geo)
{
  __shared__ float w1s[9*256];
  __shared__ float b1s[256], g1s[256], be1s[256];
  __shared__ float b2s[768], g2s[768];
  __shared__ float geo_sum[768];
  __shared__ float relr[64*12];
  __shared__ float rs_sum[64], rs_ssq[64], rs_mean[64], rs_rstd[64];
  __shared__ float cis[3];
  __shared__ short h_bf[64*264];   // 256 + 8 pad per row

  const int tid = threadIdx.x;
  const int b = blockIdx.x / NN, i = blockIdx.x % NN;

  for (int x = tid; x < 9*256; x += 512) w1s[x] = w1g[x];
  if (tid < 256){ b1s[tid]=b1g[tid]; g1s[tid]=g1g[tid]; be1s[tid]=be1g[tid]; }
  for (int x = tid; x < 768; x += 512){ b2s[x]=b2g[x]; g2s[x]=g2g[x]; geo_sum[x]=0.f; }
  if (tid < 3) cis[tid] = coord[(b*NN+i)*3+tid];
  __syncthreads();

  const int wave = tid >> 6, lane = tid & 63, quad = lane >> 4, l16 = lane & 15;
  const int colbase = wave * 96 + l16;
  const float cix = cis[0], ciy = cis[1], ciz = cis[2];

  for (int jt = 0; jt < 6; ++jt){
    const int j0 = jt * 64;
    // ---- phase 1: rel rows + zero row stats
    if (tid < 64){
      int j = j0 + tid;
      float dx = cix - coord[(b*NN+j)*3+0];
      float dy = ciy - coord[(b*NN+j)*3+1];
      float dz = ciz - coord[(b*NN+j)*3+2];
      float dist = sqrtf(dx*dx + dy*dy + dz*dz);
      float inv = 1.f / fmaxf(dist, 1e-12f);
      float x = dx*inv, y = dy*inv, z = dz*inv;
      float* rr = &relr[tid*12];
      rr[0]=dist; rr[1]=x; rr[2]=y; rr[3]=z; rr[4]=0.f; rr[5]=0.f;
      rr[6]=y*z; rr[7]=x*y; rr[8]=x*z;
    } else if (tid < 192){
      int t = tid & 63; rs_sum[t]=0.f; rs_ssq[t]=0.f;
    }
    __syncthreads();
    // ---- phase 2: mm1 (9->256) + LN + ReLU -> h_bf (bf16)
    {
      const int row = tid >> 3, p = tid & 7;
      float rl[9];
      #pragma unroll
      for (int k2=0;k2<9;++k2) rl[k2] = relr[row*12+k2];
      float hv[32]; float s=0.f, ss=0.f;
      #pragma unroll
      for (int cc=0;cc<32;++cc){
        int c = p*32 + cc;
        float a = b1s[c];
        #pragma unroll
        for (int k2=0;k2<9;++k2) a += rl[k2]*w1s[k2*256+c];
        hv[cc]=a; s+=a; ss+=a*a;
      }
      s += __shfl_xor(s,1); ss += __shfl_xor(ss,1);
      s += __shfl_xor(s,2); ss += __shfl_xor(ss,2);
      s += __shfl_xor(s,4); ss += __shfl_xor(ss,4);
      float mean = s*(1.f/256.f);
      float var  = ss*(1.f/256.f) - mean*mean;
      float rstd = rsqrtf(var + 1e-5f);
      #pragma unroll
      for (int cc=0;cc<32;++cc){
        int c = p*32 + cc;
        float hn = (hv[cc]-mean)*rstd*g1s[c] + be1s[c];
        h_bf[row*264 + c] = (short)f_bits(fmaxf(hn, 0.f));
      }
    }
    __syncthreads();
    // ---- phase 3: mm2 (256->768) via MFMA, wave owns 96 cols x 64 rows
    f32x4 acc[4][6];
    #pragma unroll
    for (int rb=0;rb<4;++rb)
      #pragma unroll
      for (int cb=0;cb<6;++cb) acc[rb][cb] = (f32x4){0.f,0.f,0.f,0.f};
    for (int ks=0;ks<8;++ks){
      bf16x8 af[4];
      #pragma unroll
      for (int rb=0;rb<4;++rb)
        af[rb] = *(const bf16x8*)&h_bf[(rb*16 + l16)*264 + ks*32 + quad*8];
      bf16x8 bfv[6];
      #pragma unroll
      for (int cb=0;cb<6;++cb)
        bfv[cb] = *(const bf16x8*)&w2T[(size_t)(colbase + cb*16)*256 + ks*32 + quad*8];
      #pragma unroll
      for (int rb=0;rb<4;++rb)
        #pragma unroll
        for (int cb=0;cb<6;++cb)
          acc[rb][cb] = __builtin_amdgcn_mfma_f32_16x16x32_bf16(af[rb], bfv[cb], acc[rb][cb], 0,0,0);
    }
    // + b2, then per-row (j) stats over 768 cols
    #pragma unroll
    for (int cb=0;cb<6;++cb){
      float bb = b2s[colbase + cb*16];
      #pragma unroll
      for (int rb=0;rb<4;++rb){
        acc[rb][cb][0]+=bb; acc[rb][cb][1]+=bb; acc[rb][cb][2]+=bb; acc[rb][cb][3]+=bb;
      }
    }
    #pragma unroll
    for (int rb=0;rb<4;++rb){
      #pragma unroll
      for (int r=0;r<4;++r){
        float s = 0.f, q = 0.f;
        #pragma unroll
        for (int cb=0;cb<6;++cb){ float v = acc[rb][cb][r]; s += v; q += v*v; }
        s += __shfl_xor(s,1); q += __shfl_xor(q,1);
        s += __shfl_xor(s,2); q += __shfl_xor(q,2);
        s += __shfl_xor(s,4); q += __shfl_xor(q,4);
        s += __shfl_xor(s,8); q += __shfl_xor(q,8);
        if (l16 == 0){
          atomicAdd(&rs_sum[rb*16 + quad*4 + r], s);
          atomicAdd(&rs_ssq[rb*16 + quad*4 + r], q);
        }
      }
    }
    __syncthreads();
    if (tid < 64){
      float m = rs_sum[tid]*(1.f/768.f);
      float v = rs_ssq[tid]*(1.f/768.f) - m*m;
      rs_mean[tid] = m; rs_rstd[tid] = rsqrtf(v + 1e-5f);
    }
    __syncthreads();
    // ---- phase 4: normalize, scale by g2, accumulate column sums over j
    {
      float mm_[4][4], rr_[4][4];
      #pragma unroll
      for (int rb=0;rb<4;++rb)
        #pragma unroll
        for (int r=0;r<4;++r){ int row = rb*16 + quad*4 + r; mm_[rb][r]=rs_mean[row]; rr_[rb][r]=rs_rstd[row]; }
      #pragma unroll
      for (int cb=0;cb<6;++cb){
        int col = colbase + cb*16;
        float cs = 0.f;
        #pragma unroll
        for (int rb=0;rb<4;++rb)
          #pragma unroll
          for (int r=0;r<4;++r) cs += (acc[rb][cb][r]-mm_[rb][r])*rr_[rb][r];
        cs *= g2s[col];
        cs += __shfl_xor(cs,16);
        cs += __shfl_xor(cs,32);
        if (quad == 0) geo_sum[col] += cs;
      }
    }
    __syncthreads();
  }
  for (int c = tid; c < 768; c += 512)
    geo[(size_t)(b*NN+i)*DD + c] = f_bits(geo_sum[c]*(1.f/384.f) + be2g[c]);
}

// ---------------- per-superpoint scatter mean ----------------
__global__ __launch_bounds__(256) void k_scatter(
    const int* __restrict__ lab, const float* __restrict__ feat,
    const unsigned short* __restrict__ geo,
    float* __restrict__ meanf, float* __restrict__ meang, float* __restrict__ cntw)
{
  __shared__ int ls[NN];
  __shared__ float sf[DD], sg[DD];
  __shared__ int cnt;
  const int tid = threadIdx.x;
  const int b = blockIdx.x / SS, s = blockIdx.x % SS;
  for (int n = tid; n < NN; n += 256) ls[n] = lab[b*NN + n];
  for (int c = tid; c < DD; c += 256){ sf[c]=0.f; sg[c]=0.f; }
  if (tid == 0) cnt = 0;
  __syncthreads();
  for (int n = 0; n < NN; ++n){
    if (ls[n] == s){
      if (tid == 0) ++cnt;
      const float* fr = feat + (size_t)(b*NN+n)*DD;
      const unsigned short* gr = geo + (size_t)(b*NN+n)*DD;
      for (int c = tid; c < DD; c += 256){ sf[c] += fr[c]; sg[c] += bits_f(gr[c]); }
    }
  }
  __syncthreads();
  float cf = (float)cnt;
  float denom = fmaxf(cf, 1.f);
  size_t base = (size_t)(b*SS+s)*DD;
  for (int c = tid; c < DD; c += 256){ meanf[base+c] = sf[c]/denom; meang[base+c] = sg[c]/denom; }
  if (tid == 0) cntw[b*SS+s] = cf;
}

// ---------------- aggregator MLP + combine with mean_g ----------------
__global__ __launch_bounds__(256) void k_agg(
    const float* __restrict__ meanf, const float* __restrict__ meang,
    const float* __restrict__ w1g, const float* __restrict__ b1g,
    const float* __restrict__ g1g, const float* __restrict__ be1g,
    const float* __restrict__ w2g, const float* __restrict__ b2g,
    const float* __restrict__ g2g, const float* __restrict__ be2g,
    float* __restrict__ comb)
{
  __shared__ float xr[DD];
  __shared__ float hr[HH];
  __shared__ float red[8];
  const int tid = threadIdx.x;
  const size_t base = (size_t)blockIdx.x * DD;
  for (int c = tid; c < DD; c += 256) xr[c] = meanf[base + c];
  __syncthreads();
  float a = b1g[tid];
  #pragma unroll 4
  for (int k = 0; k < DD; ++k) a += xr[k]*w1g[k*HH + tid];
  float s = a, q = a*a;
  for (int m = 32; m >= 1; m >>= 1){ s += __shfl_xor(s,m); q += __shfl_xor(q,m); }
  if ((tid & 63) == 0){ red[tid>>6] = s; red[4+(tid>>6)] = q; }
  __syncthreads();
  s = red[0]+red[1]+red[2]+red[3]; q = red[4]+red[5]+red[6]+red[7];
  float mean = s*(1.f/HH), var = q*(1.f/HH) - mean*mean, rstd = rsqrtf(var + 1e-5f);
  float h = fmaxf((a-mean)*rstd*g1g[tid] + be1g[tid], 0.f);
  hr[tid] = h;
  __syncthreads();
  float a2[3];
  #pragma unroll
  for (int u = 0; u < 3; ++u){
    int c = tid + 256*u;
    float t = b2g[c];
    #pragma unroll 4
    for (int k = 0; k < HH; ++k) t += hr[k]*w2g[k*DD + c];
    a2[u] = t;
  }
  float s2 = a2[0]+a2[1]+a2[2], q2 = a2[0]*a2[0]+a2[1]*a2[1]+a2[2]*a2[2];
  for (int m = 32; m >= 1; m >>= 1){ s2 += __shfl_xor(s2,m); q2 += __shfl_xor(q2,m); }
  __syncthreads();
  if ((tid & 63) == 0){ red[tid>>6] = s2; red[4+(tid>>6)] = q2; }
  __syncthreads();
  s2 = red[0]+red[1]+red[2]+red[3]; q2 = red[4]+red[5]+red[6]+red[7];
  float mean2 = s2*(1.f/DD), rstd2 = rsqrtf(q2*(1.f/DD) - mean2*mean2 + 1e-5f);
  #pragma unroll
  for (int u = 0; u < 3; ++u){
    int c = tid + 256*u;
    comb[base + c] = (a2[u]-mean2)*rstd2*g2g[c] + be2g[c] + meang[base + c];
  }
}

// ---------------- gather + enhanced (fp32 out) ----------------
__global__ void k_enhance(const float* __restrict__ feat, const int* __restrict__ lab,
                          const float* __restrict__ cntw, const float* __restrict__ comb,
                          float* __restrict__ enh)
{
  int idx = blockIdx.x * 256 + threadIdx.x;
  int c = idx % DD; int bn = idx / DD; int b = bn / NN;
  int l = lab[bn];
  float f = feat[idx];
  float cg = comb[(size_t)(b*SS + l)*DD + c];
  float cnt = cntw[b*SS + l];
  enh[idx] = (cnt >= 2.0f) ? (0.7f*f + 0.3f*cg) : f;
}

// ---------------- q/k/v projections (row GEMM, 4 rows per WG); q pre-scaled, bf16 out ----------------
__global__ __launch_bounds__(256) void k_qkv(
    const float* __restrict__ enh, const unsigned short* __restrict__ geo,
    const float* __restrict__ wq, const float* __restrict__ bq,
    const float* __restrict__ wk, const float* __restrict__ bk,
    const float* __restrict__ wv, const float* __restrict__ bv,
    unsigned short* __restrict__ qo, unsigned short* __restrict__ ko, unsigned short* __restrict__ vo)
{
  __shared__ float xs[4*DD];
  const int tid = threadIdx.x;
  const int m = blockIdx.x / 192, rb = blockIdx.x % 192;
  const float* W = (m == 0) ? wq : (m == 1 ? wk : wv);
  const float* Bv = (m == 0) ? bq : (m == 1 ? bk : bv);
  unsigned short* Y = (m == 0) ? qo : (m == 1 ? ko : vo);
  const float oscale = (m == 0) ? 0.10206207261596577f : 1.0f;   // q pre-scaled by 1/sqrt(96)
  const size_t r0 = (size_t)rb * 4;
  if (m == 0){
    for (int x = tid; x < 4*DD; x += 256) xs[x] = enh[r0*DD + x];
  } else {
    for (int x = tid; x < 4*DD; x += 256) xs[x] = bits_f(geo[r0*DD + x]);
  }
  __syncthreads();
  float acc[4][3];
  {
    float b0 = Bv[tid], b1 = Bv[tid+256], b2 = Bv[tid+512];
    #pragma unroll
    for (int r = 0; r < 4; ++r){ acc[r][0]=b0; acc[r][1]=b1; acc[r][2]=b2; }
  }
  #pragma unroll 4
  for (int k = 0; k < DD; ++k){
    float w0 = W[(size_t)k*DD + tid];
    float w1 = W[(size_t)k*DD + tid + 256];
    float w2 = W[(size_t)k*DD + tid + 512];
    float x0 = xs[k], x1 = xs[DD+k], x2 = xs[2*DD+k], x3 = xs[3*DD+k];
    acc[0][0]+=x0*w0; acc[0][1]+=x0*w1; acc[0][2]+=x0*w2;
    acc[1][0]+=x1*w0; acc[1][1]+=x1*w1; acc[1][2]+=x1*w2;
    acc[2][0]+=x2*w0; acc[2][1]+=x2*w1; acc[2][2]+=x2*w2;
    acc[3][0]+=x3*w0; acc[3][1]+=x3*w1; acc[3][2]+=x3*w2;
  }
  #pragma unroll
  for (int r = 0; r < 4; ++r){
    Y[(r0+r)*DD + tid]       = f_bits(acc[r][0]*oscale);
    Y[(r0+r)*DD + tid + 256] = f_bits(acc[r][1]*oscale);
    Y[(r0+r)*DD + tid + 512] = f_bits(acc[r][2]*oscale);
  }
}

// ---------------- attention: per (b, head, 32-q tile); bf16 K/V tiles in LDS ----------------
__global__ __launch_bounds__(256) void k_attn(
    const unsigned short* __restrict__ qws, const unsigned short* __restrict__ kws,
    const unsigned short* __restrict__ vws, unsigned short* __restrict__ ows)
{
  __shared__ short kt[64*104];
  __shared__ short vt[64*104];
  __shared__ float st[32*66];
  __shared__ float lsum[32];
  const int tid = threadIdx.x;
  const int blk = blockIdx.x;
  const int b = blk / (NHH*12); int rem = blk % (NHH*12);
  const int h = rem / 12; const int qt = rem % 12; const int q0 = qt*32;
  const int sq = tid >> 3, jp = tid & 7;        // score mapping
  const int qp = tid >> 4, dp = tid & 15;       // PV mapping
  unsigned qreg[48];
  {
    const unsigned* qr = (const unsigned*)(qws + (size_t)(b*NN + q0 + sq)*DD + h*DHH);
    #pragma unroll
    for (int d2 = 0; d2 < 48; ++d2) qreg[d2] = qr[d2];
  }
  if (tid < 32) lsum[tid] = 0.f;
  float Oacc[2][6];
  #pragma unroll
  for (int a = 0; a < 2; ++a)
    #pragma unroll
    for (int m = 0; m < 6; ++m) Oacc[a][m] = 0.f;

  for (int jt = 0; jt < 6; ++jt){
    const int j0 = jt * 64;
    __syncthreads();   // protect kt/vt/st from previous iteration readers
    for (int x = tid; x < 64*48; x += 256){
      int jl = x / 48, du = x % 48;
      size_t rowoff = (size_t)(b*NN + j0 + jl)*DD + h*DHH;
      ((unsigned*)&kt[jl*104])[du] = ((const unsigned*)(kws + rowoff))[du];
      ((unsigned*)&vt[jl*104])[du] = ((const unsigned*)(vws + rowoff))[du];
    }
    __syncthreads();
    // scores + exp
    float lpart = 0.f;
    #pragma unroll
    for (int jj = 0; jj < 8; ++jj){
      int j = jp*8 + jj;
      const uint4* kr4 = (const uint4*)&kt[j*104];
      float s = 0.f;
      #pragma unroll
      for (int d4 = 0; d4 < 12; ++d4){
        uint4 kk = kr4[d4];
        unsigned q0r = qreg[4*d4], q1r = qreg[4*d4+1], q2r = qreg[4*d4+2], q3r = qreg[4*d4+3];
        s += lo_f(kk.x)*lo_f(q0r) + hi_f(kk.x)*hi_f(q0r);
        s += lo_f(kk.y)*lo_f(q1r) + hi_f(kk.y)*hi_f(q1r);
        s += lo_f(kk.z)*lo_f(q2r) + hi_f(kk.z)*hi_f(q2r);
        s += lo_f(kk.w)*lo_f(q3r) + hi_f(kk.w)*hi_f(q3r);
      }
      float p = __expf(s);
      st[sq*66 + j] = p;
      lpart += p;
    }
    lpart += __shfl_xor(lpart,1);
    lpart += __shfl_xor(lpart,2);
    lpart += __shfl_xor(lpart,4);
    if (jp == 0) lsum[sq] += lpart;
    __syncthreads();
    // PV: thread owns q = {2qp, 2qp+1}, d = dp*6 .. +6
    #pragma unroll 4
    for (int j = 0; j < 64; ++j){
      float p0 = st[(2*qp)*66 + j];
      float p1 = st[(2*qp+1)*66 + j];
      const unsigned* vr = (const unsigned*)&vt[j*104 + dp*6];
      #pragma unroll
      for (int m = 0; m < 3; ++m){
        unsigned vv = vr[m];
        float v0 = lo_f(vv), v1 = hi_f(vv);
        Oacc[0][2*m]   += p0*v0; Oacc[0][2*m+1] += p0*v1;
        Oacc[1][2*m]   += p1*v0; Oacc[1][2*m+1] += p1*v1;
      }
    }
  }
  __syncthreads();
  float l0 = 1.f / lsum[2*qp], l1 = 1.f / lsum[2*qp+1];
  size_t ob = (size_t)(b*NN + q0)*DD + h*DHH + dp*6;
  #pragma unroll
  for (int m = 0; m < 6; ++m){
    ows[ob + (size_t)(2*qp)*DD + m]   = f_bits(Oacc[0][m]*l0);
    ows[ob + (size_t)(2*qp+1)*DD + m] = f_bits(Oacc[1][m]*l1);
  }
}

// ---------------- output projection + residual, write fp32 ----------------
__global__ __launch_bounds__(256) void k_out(
    const unsigned short* __restrict__ ows, const float* __restrict__ enh,
    const float* __restrict__ wo, const float* __restrict__ bo,
    float* __restrict__ out)
{
  __shared__ float xs[4*DD];
  const int tid = threadIdx.x;
  const size_t r0 = (size_t)blockIdx.x * 4;
  for (int x = tid; x < 4*DD; x += 256) xs[x] = bits_f(ows[r0*DD + x]);
  __syncthreads();
  float acc[4][3];
  {
    float b0 = bo[tid], b1 = bo[tid+256], b2 = bo[tid+512];
    #pragma unroll
    for (int r = 0; r < 4; ++r){ acc[r][0]=b0; acc[r][1]=b1; acc[r][2]=b2; }
  }
  #pragma unroll 4
  for (int k = 0; k < DD; ++k){
    float w0 = wo[(size_t)k*DD + tid];
    float w1 = wo[(size_t)k*DD + tid + 256];
    float w2 = wo[(size_t)k*DD + tid + 512];
    float x0 = xs[k], x1 = xs[DD+k], x2 = xs[2*DD+k], x3 = xs[3*DD+k];
    acc[0][0]+=x0*w0; acc[0][1]+=x0*w1; acc[0][2]+=x0*w2;
    acc[1][0]+=x1*w0; acc[1][1]+=x1*w1; acc[1][2]+=x1*w2;
    acc[2][0]+=x2*w0; acc[2][1]+=x2*w1; acc[2][2]+=x2*w2;
    acc[3][0]+=x3*w0; acc[3][1]+=x3*w1; acc[3][2]+=x3*w2;
  }
  #pragma unroll
  for (int r = 0; r < 4; ++r){
    #pragma unroll
    for (int u = 0; u < 3; ++u){
      size_t idx = (r0+r)*DD + tid + 256*u;
      out[idx] = enh[idx] + 0.5f*acc[r][u];
    }
  }
}

extern "C" void kernel_launch(void* const* d_in, const int* in_sizes, int n_in,
                              void* d_out, int out_size, void* d_ws, size_t ws_size,
                              hipStream_t stream) {
  const float* coord = (const float*)d_in[0];
  const float* feat  = (const float*)d_in[1];
  const int*   lab   = (const int*)d_in[2];
  const float* ge_w1 = (const float*)d_in[3];
  const float* ge_b1 = (const float*)d_in[4];
  const float* ge_g1 = (const float*)d_in[5];
  const float* ge_be1= (const float*)d_in[6];
  const float* ge_w2 = (const float*)d_in[7];
  const float* ge_b2 = (const float*)d_in[8];
  const float* ge_g2 = (const float*)d_in[9];
  const float* ge_be2= (const float*)d_in[10];
  const float* ag_w1 = (const float*)d_in[11];
  const float* ag_b1 = (const float*)d_in[12];
  const float* ag_g1 = (const float*)d_in[13];
  const float* ag_be1= (const float*)d_in[14];
  const float* ag_w2 = (const float*)d_in[15];
  const float* ag_b2 = (const float*)d_in[16];
  const float* ag_g2 = (const float*)d_in[17];
  const float* ag_be2= (const float*)d_in[18];
  const float* wq = (const float*)d_in[19];
  const float* bq = (const float*)d_in[20];
  const float* wk = (const float*)d_in[21];
  const float* bk = (const float*)d_in[22];
  const float* wv = (const float*)d_in[23];
  const float* bv = (const float*)d_in[24];
  const float* wo = (const float*)d_in[25];
  const float* bo = (const float*)d_in[26];

  // Workspace layout (8,258,048 B total). geo region reused for ow (geo's
  // last reader k_qkv runs before k_attn); w2T region reused for meanf
  // (w2T's last reader k_geo runs before k_scatter).
  char* w = (char*)d_ws;
  unsigned short* geo_bf = (unsigned short*)(w);             // 1,179,648 B  [also ow]
  float*          enh_f  = (float*)(w + 1179648);            // 2,359,296 B
  unsigned short* qw_bf  = (unsigned short*)(w + 3538944);   // 1,179,648 B
  unsigned short* kw_bf  = (unsigned short*)(w + 4718592);   // 1,179,648 B
  unsigned short* vw_bf  = (unsigned short*)(w + 5898240);   // 1,179,648 B
  short*          w2T    = (short*)(w + 7077888);            //   393,216 B  [also meanf]
  float*          meanf  = (float*)(w + 7077888);            //   393,216 B
  float*          meang  = (float*)(w + 7471104);            //   393,216 B
  float*          comb   = (float*)(w + 7864320);            //   393,216 B
  float*          cntw   = (float*)(w + 8257536);            //       512 B
  unsigned short* ow_bf  = geo_bf;

  hipLaunchKernelGGL(k_prep,    dim3(768),  dim3(256), 0, stream, ge_w2, w2T);
  hipLaunchKernelGGL(k_geo,     dim3(768),  dim3(512), 0, stream,
                     coord, ge_w1, ge_b1, ge_g1, ge_be1, ge_b2, ge_g2, ge_be2, w2T, geo_bf);
  hipLaunchKernelGGL(k_scatter, dim3(128),  dim3(256), 0, stream,
                     lab, feat, geo_bf, meanf, meang, cntw);
  hipLaunchKernelGGL(k_agg,     dim3(128),  dim3(256), 0, stream,
                     meanf, meang, ag_w1, ag_b1, ag_g1, ag_be1, ag_w2, ag_b2, ag_g2, ag_be2, comb);
  hipLaunchKernelGGL(k_enhance, dim3(2304), dim3(256), 0, stream,
                     feat, lab, cntw, comb, enh_f);
  hipLaunchKernelGGL(k_qkv,     dim3(576),  dim3(256), 0, stream,
                     enh_f, geo_bf, wq, bq, wk, bk, wv, bv, qw_bf, kw_bf, vw_bf);
  hipLaunchKernelGGL(k_attn,    dim3(192),  dim3(256), 0, stream,
                     qw_bf, kw_bf, vw_bf, ow_bf);
  hipLaunchKernelGGL(k_out,     dim3(192),  dim3(256), 0, stream,
                     ow_bf, enh_f, wo, bo, (float*)d_out);
}

// Round 5
// 913.795 us; speedup vs baseline: 1.2368x; 1.2368x over previous
//
#include <hip/hip_runtime.h>
#include <hip/hip_bf16.h>
#include <stdint.h>
#include <stddef.h>

#define BB 2
#define NN 384
#define DD 768
#define HH 256
#define SS 64
#define NHH 8
#define DHH 96

typedef __attribute__((ext_vector_type(8))) short bf16x8;
typedef __attribute__((ext_vector_type(4))) float f32x4;

__device__ __forceinline__ float bits_f(unsigned short u){
  unsigned x = ((unsigned)u) << 16; float f; __builtin_memcpy(&f, &x, 4); return f;
}
__device__ __forceinline__ unsigned short f_bits(float a){
  unsigned x; __builtin_memcpy(&x, &a, 4);
  unsigned r = x + 0x7fffu + ((x >> 16) & 1u);
  return (unsigned short)(r >> 16);
}
__device__ __forceinline__ float lo_f(unsigned u){ unsigned x = u << 16; float f; __builtin_memcpy(&f,&x,4); return f; }
__device__ __forceinline__ float hi_f(unsigned u){ unsigned x = u & 0xffff0000u; float f; __builtin_memcpy(&f,&x,4); return f; }

// ---------------- prep: w2T transpose->bf16 + zero geo_acc ----------------
__global__ void k_prep(const float* __restrict__ w2, short* __restrict__ w2T,
                       float* __restrict__ ga){
  int idx = blockIdx.x * 256 + threadIdx.x;           // 0 .. 196607
  int d = idx >> 8, k = idx & 255;
  w2T[idx] = (short)f_bits(w2[k * DD + d]);
  ga[idx] = 0.f; ga[idx + 196608] = 0.f; ga[idx + 393216] = 0.f;
}

// ---------------- fused geometric encoder; WG = (b,i,jt), 64 j-rows ----------------
__global__ __launch_bounds__(512) void k_geo(
    const float* __restrict__ coord,
    const float* __restrict__ w1g,
    const float* __restrict__ b1g, const float* __restrict__ g1g,
    const float* __restrict__ be1g,
    const float* __restrict__ b2g, const float* __restrict__ g2g,
    const short* __restrict__ w2T, float* __restrict__ geo_acc)
{
  __shared__ float w1s[9*256];
  __shared__ float b1s[256], g1s[256], be1s[256];
  __shared__ short h_bf[64*256];   // chunk-swizzled: phys_chunk=(k8+row)&31
  __shared__ float relr[64*12];
  __shared__ float rs_sum[64], rs_ssq[64], rs_mean[64], rs_rstd[64];

  const int tid = threadIdx.x;
  const int blk = blockIdx.x;
  const int pair = blk % 768;        // b*384+i  (consecutive blocks -> different XCDs)
  const int jt   = blk / 768;        // 0..5
  const int j0 = jt * 64;

  for (int x = tid; x < 9*256; x += 512) w1s[x] = w1g[x];
  if (tid < 256){ b1s[tid]=b1g[tid]; g1s[tid]=g1g[tid]; be1s[tid]=be1g[tid]; }
  const int b = pair / NN;
  const float cix = coord[pair*3+0], ciy = coord[pair*3+1], ciz = coord[pair*3+2];
  if (tid < 64){
    int j = j0 + tid;
    float dx = cix - coord[(b*NN+j)*3+0];
    float dy = ciy - coord[(b*NN+j)*3+1];
    float dz = ciz - coord[(b*NN+j)*3+2];
    float dist = sqrtf(dx*dx + dy*dy + dz*dz);
    float inv = 1.f / fmaxf(dist, 1e-12f);
    float x = dx*inv, y = dy*inv, z = dz*inv;
    float* rr = &relr[tid*12];
    rr[0]=dist; rr[1]=x; rr[2]=y; rr[3]=z; rr[4]=0.f; rr[5]=0.f;
    rr[6]=y*z; rr[7]=x*y; rr[8]=x*z;
  } else if (tid < 192){
    int t = tid & 63; rs_sum[t]=0.f; rs_ssq[t]=0.f;
  }
  __syncthreads();

  // ---- phase 2: mm1 (9->256) + LN + ReLU -> h_bf. thread p owns cols cc*8+p.
  {
    const int row = tid >> 3, p = tid & 7;
    float rl[9];
    #pragma unroll
    for (int k2=0;k2<9;++k2) rl[k2] = relr[row*12+k2];
    float hv[32]; float s=0.f, ss=0.f;
    #pragma unroll
    for (int cc=0;cc<32;++cc){
      int c = cc*8 + p;
      float a = b1s[c];
      #pragma unroll
      for (int k2=0;k2<9;++k2) a += rl[k2]*w1s[k2*256+c];
      hv[cc]=a; s+=a; ss+=a*a;
    }
    s += __shfl_xor(s,1); ss += __shfl_xor(ss,1);
    s += __shfl_xor(s,2); ss += __shfl_xor(ss,2);
    s += __shfl_xor(s,4); ss += __shfl_xor(ss,4);
    float mean = s*(1.f/256.f);
    float var  = ss*(1.f/256.f) - mean*mean;
    float rstd = rsqrtf(var + 1e-5f);
    #pragma unroll
    for (int cc=0;cc<32;++cc){
      int c = cc*8 + p;
      float hn = (hv[cc]-mean)*rstd*g1s[c] + be1s[c];
      h_bf[row*256 + ((cc + row)&31)*8 + p] = (short)f_bits(fmaxf(hn, 0.f));
    }
  }
  __syncthreads();

  // ---- phase 3: mm2 (256->768) via MFMA; wave owns 96 cols x 64 rows
  const int wave = tid >> 6, lane = tid & 63, quad = lane >> 4, l16 = lane & 15;
  const int colbase = wave * 96 + l16;
  f32x4 acc[4][6];
  #pragma unroll
  for (int rb=0;rb<4;++rb)
    #pragma unroll
    for (int cb=0;cb<6;++cb) acc[rb][cb] = (f32x4){0.f,0.f,0.f,0.f};
  for (int ks=0;ks<8;++ks){
    bf16x8 af[4];
    #pragma unroll
    for (int rb=0;rb<4;++rb){
      int row = rb*16 + l16;
      af[rb] = *(const bf16x8*)&h_bf[row*256 + (((ks*4 + quad) + row)&31)*8];
    }
    bf16x8 bfv[6];
    #pragma unroll
    for (int cb=0;cb<6;++cb)
      bfv[cb] = *(const bf16x8*)&w2T[(size_t)(colbase + cb*16)*256 + ks*32 + quad*8];
    #pragma unroll
    for (int rb=0;rb<4;++rb)
      #pragma unroll
      for (int cb=0;cb<6;++cb)
        acc[rb][cb] = __builtin_amdgcn_mfma_f32_16x16x32_bf16(af[rb], bfv[cb], acc[rb][cb], 0,0,0);
  }
  // + b2, then per-row (j) stats over 768 cols
  #pragma unroll
  for (int cb=0;cb<6;++cb){
    float bb = b2g[colbase + cb*16];
    #pragma unroll
    for (int rb=0;rb<4;++rb){
      acc[rb][cb][0]+=bb; acc[rb][cb][1]+=bb; acc[rb][cb][2]+=bb; acc[rb][cb][3]+=bb;
    }
  }
  #pragma unroll
  for (int rb=0;rb<4;++rb){
    #pragma unroll
    for (int r=0;r<4;++r){
      float s = 0.f, q = 0.f;
      #pragma unroll
      for (int cb=0;cb<6;++cb){ float v = acc[rb][cb][r]; s += v; q += v*v; }
      s += __shfl_xor(s,1); q += __shfl_xor(q,1);
      s += __shfl_xor(s,2); q += __shfl_xor(q,2);
      s += __shfl_xor(s,4); q += __shfl_xor(q,4);
      s += __shfl_xor(s,8); q += __shfl_xor(q,8);
      if (l16 == 0){
        atomicAdd(&rs_sum[rb*16 + quad*4 + r], s);
        atomicAdd(&rs_ssq[rb*16 + quad*4 + r], q);
      }
    }
  }
  __syncthreads();
  if (tid < 64){
    float m = rs_sum[tid]*(1.f/768.f);
    float v = rs_ssq[tid]*(1.f/768.f) - m*m;
    rs_mean[tid] = m; rs_rstd[tid] = rsqrtf(v + 1e-5f);
  }
  __syncthreads();
  // ---- phase 4: normalize, scale by g2, column-sum over 64 rows -> global atomics
  {
    float mm_[4][4], rr_[4][4];
    #pragma unroll
    for (int rb=0;rb<4;++rb)
      #pragma unroll
      for (int r=0;r<4;++r){ int row = rb*16 + quad*4 + r; mm_[rb][r]=rs_mean[row]; rr_[rb][r]=rs_rstd[row]; }
    float* gp = geo_acc + (size_t)pair * DD;
    #pragma unroll
    for (int cb=0;cb<6;++cb){
      int col = colbase + cb*16;
      float cs = 0.f;
      #pragma unroll
      for (int rb=0;rb<4;++rb)
        #pragma unroll
        for (int r=0;r<4;++r) cs += (acc[rb][cb][r]-mm_[rb][r])*rr_[rb][r];
      cs *= g2g[col];
      cs += __shfl_xor(cs,16);
      cs += __shfl_xor(cs,32);
      if (quad == 0) atomicAdd(&gp[col], cs);
    }
  }
}

// ---------------- finalize geo: /384 + be2, write bf16 ----------------
__global__ void k_geofin(const float* __restrict__ ga, const float* __restrict__ be2g,
                         unsigned short* __restrict__ geo){
  int idx4 = blockIdx.x * 256 + threadIdx.x;      // 0..147455
  float4 v = ((const float4*)ga)[idx4];
  int base = idx4 * 4;
  int col = base % DD;                             // base%4==0 and 768%4==0
  geo[base+0] = f_bits(v.x*(1.f/384.f) + be2g[col+0]);
  geo[base+1] = f_bits(v.y*(1.f/384.f) + be2g[col+1]);
  geo[base+2] = f_bits(v.z*(1.f/384.f) + be2g[col+2]);
  geo[base+3] = f_bits(v.w*(1.f/384.f) + be2g[col+3]);
}

// ---------------- per-superpoint scatter mean ----------------
__global__ __launch_bounds__(256) void k_scatter(
    const int* __restrict__ lab, const float* __restrict__ feat,
    const unsigned short* __restrict__ geo,
    float* __restrict__ meanf, float* __restrict__ meang, float* __restrict__ cntw)
{
  __shared__ int ls[NN];
  __shared__ float sf[DD], sg[DD];
  __shared__ int cnt;
  const int tid = threadIdx.x;
  const int b = blockIdx.x / SS, s = blockIdx.x % SS;
  for (int n = tid; n < NN; n += 256) ls[n] = lab[b*NN + n];
  for (int c = tid; c < DD; c += 256){ sf[c]=0.f; sg[c]=0.f; }
  if (tid == 0) cnt = 0;
  __syncthreads();
  for (int n = 0; n < NN; ++n){
    if (ls[n] == s){
      if (tid == 0) ++cnt;
      const float* fr = feat + (size_t)(b*NN+n)*DD;
      const unsigned short* gr = geo + (size_t)(b*NN+n)*DD;
      for (int c = tid; c < DD; c += 256){ sf[c] += fr[c]; sg[c] += bits_f(gr[c]); }
    }
  }
  __syncthreads();
  float cf = (float)cnt;
  float denom = fmaxf(cf, 1.f);
  size_t base = (size_t)(b*SS+s)*DD;
  for (int c = tid; c < DD; c += 256){ meanf[base+c] = sf[c]/denom; meang[base+c] = sg[c]/denom; }
  if (tid == 0) cntw[b*SS+s] = cf;
}

// ---------------- aggregator MLP + combine with mean_g ----------------
__global__ __launch_bounds__(256) void k_agg(
    const float* __restrict__ meanf, const float* __restrict__ meang,
    const float* __restrict__ w1g, const float* __restrict__ b1g,
    const float* __restrict__ g1g, const float* __restrict__ be1g,
    const float* __restrict__ w2g, const float* __restrict__ b2g,
    const float* __restrict__ g2g, const float* __restrict__ be2g,
    float* __restrict__ comb)
{
  __shared__ float xr[DD];
  __shared__ float hr[HH];
  __shared__ float red[8];
  const int tid = threadIdx.x;
  const size_t base = (size_t)blockIdx.x * DD;
  for (int c = tid; c < DD; c += 256) xr[c] = meanf[base + c];
  __syncthreads();
  float a = b1g[tid];
  #pragma unroll 4
  for (int k = 0; k < DD; ++k) a += xr[k]*w1g[k*HH + tid];
  float s = a, q = a*a;
  for (int m = 32; m >= 1; m >>= 1){ s += __shfl_xor(s,m); q += __shfl_xor(q,m); }
  if ((tid & 63) == 0){ red[tid>>6] = s; red[4+(tid>>6)] = q; }
  __syncthreads();
  s = red[0]+red[1]+red[2]+red[3]; q = red[4]+red[5]+red[6]+red[7];
  float mean = s*(1.f/HH), var = q*(1.f/HH) - mean*mean, rstd = rsqrtf(var + 1e-5f);
  float h = fmaxf((a-mean)*rstd*g1g[tid] + be1g[tid], 0.f);
  hr[tid] = h;
  __syncthreads();
  float a2[3];
  #pragma unroll
  for (int u = 0; u < 3; ++u){
    int c = tid + 256*u;
    float t = b2g[c];
    #pragma unroll 4
    for (int k = 0; k < HH; ++k) t += hr[k]*w2g[k*DD + c];
    a2[u] = t;
  }
  float s2 = a2[0]+a2[1]+a2[2], q2 = a2[0]*a2[0]+a2[1]*a2[1]+a2[2]*a2[2];
  for (int m = 32; m >= 1; m >>= 1){ s2 += __shfl_xor(s2,m); q2 += __shfl_xor(q2,m); }
  __syncthreads();
  if ((tid & 63) == 0){ red[tid>>6] = s2; red[4+(tid>>6)] = q2; }
  __syncthreads();
  s2 = red[0]+red[1]+red[2]+red[3]; q2 = red[4]+red[5]+red[6]+red[7];
  float mean2 = s2*(1.f/DD), rstd2 = rsqrtf(q2*(1.f/DD) - mean2*mean2 + 1e-5f);
  #pragma unroll
  for (int u = 0; u < 3; ++u){
    int c = tid + 256*u;
    comb[base + c] = (a2[u]-mean2)*rstd2*g2g[c] + be2g[c] + meang[base + c];
  }
}

// ---------------- gather + enhanced (fp32 out) ----------------
__global__ void k_enhance(const float* __restrict__ feat, const int* __restrict__ lab,
                          const float* __restrict__ cntw, const float* __restrict__ comb,
                          float* __restrict__ enh)
{
  int idx = blockIdx.x * 256 + threadIdx.x;
  int c = idx % DD; int bn = idx / DD; int b = bn / NN;
  int l = lab[bn];
  float f = feat[idx];
  float cg = comb[(size_t)(b*SS + l)*DD + c];
  float cnt = cntw[b*SS + l];
  enh[idx] = (cnt >= 2.0f) ? (0.7f*f + 0.3f*cg) : f;
}

// ---------------- q/k/v projections (row GEMM, 4 rows per WG); q pre-scaled, bf16 out ----------------
__global__ __launch_bounds__(256) void k_qkv(
    const float* __restrict__ enh, const unsigned short* __restrict__ geo,
    const float* __restrict__ wq, const float* __restrict__ bq,
    const float* __restrict__ wk, const float* __restrict__ bk,
    const float* __restrict__ wv, const float* __restrict__ bv,
    unsigned short* __restrict__ qo, unsigned short* __restrict__ ko, unsigned short* __restrict__ vo)
{
  __shared__ float xs[4*DD];
  const int tid = threadIdx.x;
  const int m = blockIdx.x / 192, rb = blockIdx.x % 192;
  const float* W = (m == 0) ? wq : (m == 1 ? wk : wv);
  const float* Bv = (m == 0) ? bq : (m == 1 ? bk : bv);
  unsigned short* Y = (m == 0) ? qo : (m == 1 ? ko : vo);
  const float oscale = (m == 0) ? 0.10206207261596577f : 1.0f;   // q pre-scaled by 1/sqrt(96)
  const size_t r0 = (size_t)rb * 4;
  if (m == 0){
    for (int x = tid; x < 4*DD; x += 256) xs[x] = enh[r0*DD + x];
  } else {
    for (int x = tid; x < 4*DD; x += 256) xs[x] = bits_f(geo[r0*DD + x]);
  }
  __syncthreads();
  float acc[4][3];
  {
    float b0 = Bv[tid], b1 = Bv[tid+256], b2 = Bv[tid+512];
    #pragma unroll
    for (int r = 0; r < 4; ++r){ acc[r][0]=b0; acc[r][1]=b1; acc[r][2]=b2; }
  }
  #pragma unroll 4
  for (int k = 0; k < DD; ++k){
    float w0 = W[(size_t)k*DD + tid];
    float w1 = W[(size_t)k*DD + tid + 256];
    float w2 = W[(size_t)k*DD + tid + 512];
    float x0 = xs[k], x1 = xs[DD+k], x2 = xs[2*DD+k], x3 = xs[3*DD+k];
    acc[0][0]+=x0*w0; acc[0][1]+=x0*w1; acc[0][2]+=x0*w2;
    acc[1][0]+=x1*w0; acc[1][1]+=x1*w1; acc[1][2]+=x1*w2;
    acc[2][0]+=x2*w0; acc[2][1]+=x2*w1; acc[2][2]+=x2*w2;
    acc[3][0]+=x3*w0; acc[3][1]+=x3*w1; acc[3][2]+=x3*w2;
  }
  #pragma unroll
  for (int r = 0; r < 4; ++r){
    Y[(r0+r)*DD + tid]       = f_bits(acc[r][0]*oscale);
    Y[(r0+r)*DD + tid + 256] = f_bits(acc[r][1]*oscale);
    Y[(r0+r)*DD + tid + 512] = f_bits(acc[r][2]*oscale);
  }
}

// ---------------- attention: per (b, head, 32-q tile); bf16 K/V tiles in LDS ----------------
__global__ __launch_bounds__(256) void k_attn(
    const unsigned short* __restrict__ qws, const unsigned short* __restrict__ kws,
    const unsigned short* __restrict__ vws, unsigned short* __restrict__ ows)
{
  __shared__ short kt[64*104];
  __shared__ short vt[64*104];
  __shared__ float st[32*66];
  __shared__ float lsum[32];
  const int tid = threadIdx.x;
  const int blk = blockIdx.x;
  const int b = blk / (NHH*12); int rem = blk % (NHH*12);
  const int h = rem / 12; const int qt = rem % 12; const int q0 = qt*32;
  const int sq = tid >> 3, jp = tid & 7;        // score mapping
  const int qp = tid >> 4, dp = tid & 15;       // PV mapping
  unsigned qreg[48];
  {
    const unsigned* qr = (const unsigned*)(qws + (size_t)(b*NN + q0 + sq)*DD + h*DHH);
    #pragma unroll
    for (int d2 = 0; d2 < 48; ++d2) qreg[d2] = qr[d2];
  }
  if (tid < 32) lsum[tid] = 0.f;
  float Oacc[2][6];
  #pragma unroll
  for (int a = 0; a < 2; ++a)
    #pragma unroll
    for (int m = 0; m < 6; ++m) Oacc[a][m] = 0.f;

  for (int jt = 0; jt < 6; ++jt){
    const int j0 = jt * 64;
    __syncthreads();   // protect kt/vt/st from previous iteration readers
    for (int x = tid; x < 64*48; x += 256){
      int jl = x / 48, du = x % 48;
      size_t rowoff = (size_t)(b*NN + j0 + jl)*DD + h*DHH;
      ((unsigned*)&kt[jl*104])[du] = ((const unsigned*)(kws + rowoff))[du];
      ((unsigned*)&vt[jl*104])[du] = ((const unsigned*)(vws + rowoff))[du];
    }
    __syncthreads();
    // scores + exp
    float lpart = 0.f;
    #pragma unroll
    for (int jj = 0; jj < 8; ++jj){
      int j = jp*8 + jj;
      const uint4* kr4 = (const uint4*)&kt[j*104];
      float s = 0.f;
      #pragma unroll
      for (int d4 = 0; d4 < 12; ++d4){
        uint4 kk = kr4[d4];
        unsigned q0r = qreg[4*d4], q1r = qreg[4*d4+1], q2r = qreg[4*d4+2], q3r = qreg[4*d4+3];
        s += lo_f(kk.x)*lo_f(q0r) + hi_f(kk.x)*hi_f(q0r);
        s += lo_f(kk.y)*lo_f(q1r) + hi_f(kk.y)*hi_f(q1r);
        s += lo_f(kk.z)*lo_f(q2r) + hi_f(kk.z)*hi_f(q2r);
        s += lo_f(kk.w)*lo_f(q3r) + hi_f(kk.w)*hi_f(q3r);
      }
      float p = __expf(s);
      st[sq*66 + j] = p;
      lpart += p;
    }
    lpart += __shfl_xor(lpart,1);
    lpart += __shfl_xor(lpart,2);
    lpart += __shfl_xor(lpart,4);
    if (jp == 0) lsum[sq] += lpart;
    __syncthreads();
    // PV: thread owns q = {2qp, 2qp+1}, d = dp*6 .. +6
    #pragma unroll 4
    for (int j = 0; j < 64; ++j){
      float p0 = st[(2*qp)*66 + j];
      float p1 = st[(2*qp+1)*66 + j];
      const unsigned* vr = (const unsigned*)&vt[j*104 + dp*6];
      #pragma unroll
      for (int m = 0; m < 3; ++m){
        unsigned vv = vr[m];
        float v0 = lo_f(vv), v1 = hi_f(vv);
        Oacc[0][2*m]   += p0*v0; Oacc[0][2*m+1] += p0*v1;
        Oacc[1][2*m]   += p1*v0; Oacc[1][2*m+1] += p1*v1;
      }
    }
  }
  __syncthreads();
  float l0 = 1.f / lsum[2*qp], l1 = 1.f / lsum[2*qp+1];
  size_t ob = (size_t)(b*NN + q0)*DD + h*DHH + dp*6;
  #pragma unroll
  for (int m = 0; m < 6; ++m){
    ows[ob + (size_t)(2*qp)*DD + m]   = f_bits(Oacc[0][m]*l0);
    ows[ob + (size_t)(2*qp+1)*DD + m] = f_bits(Oacc[1][m]*l1);
  }
}

// ---------------- output projection + residual, write fp32 ----------------
__global__ __launch_bounds__(256) void k_out(
    const unsigned short* __restrict__ ows, const float* __restrict__ enh,
    const float* __restrict__ wo, const float* __restrict__ bo,
    float* __restrict__ out)
{
  __shared__ float xs[4*DD];
  const int tid = threadIdx.x;
  const size_t r0 = (size_t)blockIdx.x * 4;
  for (int x = tid; x < 4*DD; x += 256) xs[x] = bits_f(ows[r0*DD + x]);
  __syncthreads();
  float acc[4][3];
  {
    float b0 = bo[tid], b1 = bo[tid+256], b2 = bo[tid+512];
    #pragma unroll
    for (int r = 0; r < 4; ++r){ acc[r][0]=b0; acc[r][1]=b1; acc[r][2]=b2; }
  }
  #pragma unroll 4
  for (int k = 0; k < DD; ++k){
    float w0 = wo[(size_t)k*DD + tid];
    float w1 = wo[(size_t)k*DD + tid + 256];
    float w2 = wo[(size_t)k*DD + tid + 512];
    float x0 = xs[k], x1 = xs[DD+k], x2 = xs[2*DD+k], x3 = xs[3*DD+k];
    acc[0][0]+=x0*w0; acc[0][1]+=x0*w1; acc[0][2]+=x0*w2;
    acc[1][0]+=x1*w0; acc[1][1]+=x1*w1; acc[1][2]+=x1*w2;
    acc[2][0]+=x2*w0; acc[2][1]+=x2*w1; acc[2][2]+=x2*w2;
    acc[3][0]+=x3*w0; acc[3][1]+=x3*w1; acc[3][2]+=x3*w2;
  }
  #pragma unroll
  for (int r = 0; r < 4; ++r){
    #pragma unroll
    for (int u = 0; u < 3; ++u){
      size_t idx = (r0+r)*DD + tid + 256*u;
      out[idx] = enh[idx] + 0.5f*acc[r][u];
    }
  }
}

extern "C" void kernel_launch(void* const* d_in, const int* in_sizes, int n_in,
                              void* d_out, int out_size, void* d_ws, size_t ws_size,
                              hipStream_t stream) {
  const float* coord = (const float*)d_in[0];
  const float* feat  = (const float*)d_in[1];
  const int*   lab   = (const int*)d_in[2];
  const float* ge_w1 = (const float*)d_in[3];
  const float* ge_b1 = (const float*)d_in[4];
  const float* ge_g1 = (const float*)d_in[5];
  const float* ge_be1= (const float*)d_in[6];
  const float* ge_w2 = (const float*)d_in[7];
  const float* ge_b2 = (const float*)d_in[8];
  const float* ge_g2 = (const float*)d_in[9];
  const float* ge_be2= (const float*)d_in[10];
  const float* ag_w1 = (const float*)d_in[11];
  const float* ag_b1 = (const float*)d_in[12];
  const float* ag_g1 = (const float*)d_in[13];
  const float* ag_be1= (const float*)d_in[14];
  const float* ag_w2 = (const float*)d_in[15];
  const float* ag_b2 = (const float*)d_in[16];
  const float* ag_g2 = (const float*)d_in[17];
  const float* ag_be2= (const float*)d_in[18];
  const float* wq = (const float*)d_in[19];
  const float* bq = (const float*)d_in[20];
  const float* wk = (const float*)d_in[21];
  const float* bk = (const float*)d_in[22];
  const float* wv = (const float*)d_in[23];
  const float* bv = (const float*)d_in[24];
  const float* wo = (const float*)d_in[25];
  const float* bo = (const float*)d_in[26];

  // Workspace (8,258,048 B). geo_acc (fp32, 2.36MB) overlays qw+kw regions:
  // last read of geo_acc is k_geofin, which runs before k_qkv writes qw/kw.
  // geo_bf region reused as ow after k_qkv; w2T region reused as meanf after k_geo.
  char* w = (char*)d_ws;
  unsigned short* geo_bf = (unsigned short*)(w);             // 1,179,648 B  [also ow]
  float*          enh_f  = (float*)(w + 1179648);            // 2,359,296 B
  unsigned short* qw_bf  = (unsigned short*)(w + 3538944);   // 1,179,648 B  [geo_acc lo]
  unsigned short* kw_bf  = (unsigned short*)(w + 4718592);   // 1,179,648 B  [geo_acc hi]
  unsigned short* vw_bf  = (unsigned short*)(w + 5898240);   // 1,179,648 B
  short*          w2T    = (short*)(w + 7077888);            //   393,216 B  [also meanf]
  float*          meanf  = (float*)(w + 7077888);            //   393,216 B
  float*          meang  = (float*)(w + 7471104);            //   393,216 B
  float*          comb   = (float*)(w + 7864320);            //   393,216 B
  float*          cntw   = (float*)(w + 8257536);            //       512 B
  float*          geo_acc= (float*)(w + 3538944);            // 2,359,296 B overlay
  unsigned short* ow_bf  = geo_bf;

  hipLaunchKernelGGL(k_prep,    dim3(768),  dim3(256), 0, stream, ge_w2, w2T, geo_acc);
  hipLaunchKernelGGL(k_geo,     dim3(4608), dim3(512), 0, stream,
                     coord, ge_w1, ge_b1, ge_g1, ge_be1, ge_b2, ge_g2, w2T, geo_acc);
  hipLaunchKernelGGL(k_geofin,  dim3(576),  dim3(256), 0, stream, geo_acc, ge_be2, geo_bf);
  hipLaunchKernelGGL(k_scatter, dim3(128),  dim3(256), 0, stream,
                     lab, feat, geo_bf, meanf, meang, cntw);
  hipLaunchKernelGGL(k_agg,     dim3(128),  dim3(256), 0, stream,
                     meanf, meang, ag_w1, ag_b1, ag_g1, ag_be1, ag_w2, ag_b2, ag_g2, ag_be2, comb);
  hipLaunchKernelGGL(k_enhance, dim3(2304), dim3(256), 0, stream,
                     feat, lab, cntw, comb, enh_f);
  hipLaunchKernelGGL(k_qkv,     dim3(576),  dim3(256), 0, stream,
                     enh_f, geo_bf, wq, bq, wk, bk, wv, bv, qw_bf, kw_bf, vw_bf);
  hipLaunchKernelGGL(k_attn,    dim3(192),  dim3(256), 0, stream,
                     qw_bf, kw_bf, vw_bf, ow_bf);
  hipLaunchKernelGGL(k_out,     dim3(192),  dim3(256), 0, stream,
                     ow_bf, enh_f, wo, bo, (float*)d_out);
}